// Round 12
// baseline (543.685 us; speedup 1.0000x reference)
//
#include <hip/hip_runtime.h>
#include <cstdint>

// ---------------------------------------------------------------------------
// dysOpt: Davis-Yin splitting, 262144 rows x 64 vars, dynamic T.
//
// x20 u-space iteration (U = 20*(z + C), CC = 20*C):
//   m'  = clamp(U, CC, CC+20)           (= 20*(clamp(z,0,1)+C))
//   U+  = K1*m' - c[j]                  (raw c; update independent of the
//                                        row reduction)
//   Sx  = 0.05*(Sm' - 64*CC) ; t = K2*Sx - R
//   corr20 = t*(20/64) - 10 ; R+ = R - Sx + 32 ; CC+ = K1*CC + corr20
//
// ROUND-11/12 cost model (fits r2..r10 within ~10%): 3-src VALU (fma/med3)
// ~4 cyc/wave64, 2-src VOP2 ~2 cyc. pass1 is ~95% of that floor already.
// Changes: (1) float2 element loop -- upside if v_pk_add_f32 is 2-src-rate,
// worst-case scalarizes on pair regs = neutral; pins dropped, reduce back to
// r6's shfl_xor (r10's DPP+pins was 9% slower than r6). (2) fp16 checkpoint
// via cvt_pkrtz (z in [-1.5,1.5], err<=1e-3): halves ckpt traffic both ways.
// (3) probe x4 rows (32768, 2 waves/SIMD) to hide chain latency.
// r12 fix: cvt_pkrtz returns __fp16x2, not _Float16x2 (compile error only).
//
// Structure: probe -> Ts = max Tr <= T; pass1: P = Ts-2 fast iters, then
// checked to wave all-pass = ib (monotone residual => argmax wave reports
// exactly T); fp16-checkpoint z(ib), atomicMax T. pass2: resume ib -> T,
// +1 differentiable step, clamp, store.
// Check: 400*||dz||^2 = q2 - 2*dCC*q1 + 64*dCC^2 <= 400*TOL^2 = 0.04.
// ---------------------------------------------------------------------------

#ifndef JAX_PARTITIONABLE
#define JAX_PARTITIONABLE 1
#endif

#define BATCHN 262144
#define MAXIT  200
#define RPW    16                         // rows per wave (4 lanes/row)
#define NWAVES (BATCHN / RPW)             // 16384
#define PROBE_ROWS 32768
#define PROBE_WAVES (PROBE_ROWS / RPW)    // 2048

#define K1 0.9975f   // 1 - a^2
#define K2 1.9975f   // 2 - a^2

typedef float v2f __attribute__((ext_vector_type(2)));
typedef __fp16 h2v __attribute__((ext_vector_type(2)));

__device__ __forceinline__ void tf2x32(uint32_t x0, uint32_t x1,
                                       uint32_t& o0, uint32_t& o1) {
  const uint32_t k0 = 0u, k1 = 1u;                 // jax.random.key(1) -> [0,1]
  const uint32_t k2 = 0x1BD11BDAu ^ k0 ^ k1;
  x0 += k0; x1 += k1;
#define TFR(r) { x0 += x1; x1 = (x1 << (r)) | (x1 >> (32 - (r))); x1 ^= x0; }
  TFR(13) TFR(15) TFR(26) TFR(6)   x0 += k1; x1 += k2 + 1u;
  TFR(17) TFR(29) TFR(16) TFR(24)  x0 += k2; x1 += k0 + 2u;
  TFR(13) TFR(15) TFR(26) TFR(6)   x0 += k0; x1 += k1 + 3u;
  TFR(17) TFR(29) TFR(16) TFR(24)  x0 += k1; x1 += k2 + 4u;
  TFR(13) TFR(15) TFR(26) TFR(6)   x0 += k2; x1 += k0 + 5u;
#undef TFR
  o0 = x0; o1 = x1;
}

__device__ __forceinline__ float z0_at(uint32_t f) {
  uint32_t b;
#if JAX_PARTITIONABLE
  uint32_t o0, o1;
  tf2x32(0u, f, o0, o1);
  b = o0 ^ o1;
#else
  const uint32_t H = 8388608u;
  uint32_t lo = (f < H) ? f : (f - H);
  uint32_t o0, o1;
  tf2x32(lo, lo + H, o0, o1);
  b = (f < H) ? o0 : o1;
#endif
  return __uint_as_float((b >> 9) | 0x3f800000u) - 1.0f;
}

// 4-lane row reduction (lanes xor 1,2 hold one row) -- r6's proven form
__device__ __forceinline__ float reduce4(float v) {
  v += __shfl_xor(v, 1);
  v += __shfl_xor(v, 2);
  return v;
}

// ---- fast iteration: float2-paired element loop, no convergence check -----
__device__ __forceinline__ void fast_iter(v2f U[8], const v2f c[8],
                                          float& CC, float& R) {
  v2f CC2; CC2.x = CC; CC2.y = CC;
  v2f Ch2 = CC2 + 20.0f;
  v2f acc = (v2f)(0.0f);
#pragma unroll
  for (int j = 0; j < 8; ++j) {
    v2f m = __builtin_elementwise_min(
        __builtin_elementwise_max(U[j], CC2), Ch2);
    acc += m;                                          // v_pk_add_f32 (maybe)
    U[j] = __builtin_elementwise_fma((v2f)(K1), m, -c[j]);
  }
  float s = acc.x + acc.y;
  s = reduce4(s);                                      // Sm' over the row
  float Sx = 0.05f * __builtin_fmaf(-64.0f, CC, s);    // (Sm' - 64CC)/20
  float t  = __builtin_fmaf(K2, Sx, -R);
  float corr20 = __builtin_fmaf(t, 0.3125f, -10.0f);   // 20*(t/64 - 0.5)
  R = (R - Sx) + 32.0f;
  CC = __builtin_fmaf(K1, CC, corr20);
}

// ---- checked iteration: returns 400*||dz_row||^2 (replicated in the row) --
__device__ __forceinline__ float chk_iter(v2f U[8], const v2f c[8],
                                          float& CC, float& R) {
  v2f CC2; CC2.x = CC; CC2.y = CC;
  v2f Ch2 = CC2 + 20.0f;
  v2f acc = (v2f)(0.0f), q12 = (v2f)(0.0f), q22 = (v2f)(0.0f);
#pragma unroll
  for (int j = 0; j < 8; ++j) {
    v2f m = __builtin_elementwise_min(
        __builtin_elementwise_max(U[j], CC2), Ch2);
    acc += m;
    v2f un = __builtin_elementwise_fma((v2f)(K1), m, -c[j]);
    v2f d = un - U[j];
    q12 += d;
    q22 = __builtin_elementwise_fma(d, d, q22);
    U[j] = un;
  }
  float s = reduce4(acc.x + acc.y);
  float Sx = 0.05f * __builtin_fmaf(-64.0f, CC, s);
  float t  = __builtin_fmaf(K2, Sx, -R);
  float corr20 = __builtin_fmaf(t, 0.3125f, -10.0f);
  R = (R - Sx) + 32.0f;
  float CCn = __builtin_fmaf(K1, CC, corr20);
  float dCC = CCn - CC;
  CC = CCn;
  float q1 = reduce4(q12.x + q12.y);
  float q2 = reduce4(q22.x + q22.y);
  // 400*ds = q2 - 2*dCC*q1 + 64*dCC^2
  float a = __builtin_fmaf(64.0f, dCC, -2.0f * q1);
  return __builtin_fmaf(dCC, a, q2);
}

__device__ __forceinline__ void load_c(const float* __restrict__ cost,
                                       int base, v2f c[8]) {
#pragma unroll
  for (int k = 0; k < 2; ++k) {
    const float4 a = *(const float4*)(cost + base + 8 * k);
    const float4 b = *(const float4*)(cost + base + 8 * k + 4);
    c[4 * k + 0].x = a.x; c[4 * k + 0].y = a.y;
    c[4 * k + 1].x = a.z; c[4 * k + 1].y = a.w;
    c[4 * k + 2].x = b.x; c[4 * k + 2].y = b.y;
    c[4 * k + 3].x = b.z; c[4 * k + 3].y = b.w;
  }
}

__device__ __forceinline__ void init_state(const float* __restrict__ cost,
                                           int base, v2f c[8], v2f U[8],
                                           float& CC, float& R) {
  load_c(cost, base, c);
  float r = 0.0f;
#pragma unroll
  for (int j = 0; j < 8; ++j) {
    float za = z0_at((uint32_t)(base + 2 * j));
    float zb = z0_at((uint32_t)(base + 2 * j + 1));
    U[j].x = 20.0f * za;
    U[j].y = 20.0f * zb;
    r += (za + zb);
    r = __builtin_fmaf(0.05f, c[j].x + c[j].y, r);
  }
  R = reduce4(r);                               // R = Sz + a*Sc
  CC = 0.0f;
}

// --- probe: rows [0, PROBE_ROWS), checked every iter, atomicMax Ts ---------
__global__ __launch_bounds__(256, 4) void dys_probe(
    const float* __restrict__ cost, int* __restrict__ Tsample) {
  const int lane = threadIdx.x & 63;
  const int gw = blockIdx.x * 4 + (threadIdx.x >> 6);
  const int base = (gw * RPW + (lane >> 2)) * 64 + (lane & 3) * 16;

  v2f c[8], U[8];
  float CC, R;
  init_state(cost, base, c, U, CC, R);

  int ib = MAXIT;
  for (int i = 1; i <= MAXIT; ++i) {
    float ds = chk_iter(U, c, CC, R);
    if (__all(ds <= 0.04f)) { ib = i; break; }   // wave-max Tr
  }
  if (lane == 0) atomicMax(Tsample, ib);
}

// --- pass1: P fast iters, checked to wave all-pass; fp16 checkpoint --------
__global__ __launch_bounds__(256, 4) void dys_pass1(
    const float* __restrict__ cost, const int* __restrict__ Tsample,
    int* __restrict__ Tglob, int* __restrict__ TrArr,
    uint32_t* __restrict__ zh) {
  const int lane = threadIdx.x & 63;
  const int gw = blockIdx.x * 4 + (threadIdx.x >> 6);
  const int base = (gw * RPW + (lane >> 2)) * 64 + (lane & 3) * 16;

  v2f c[8], U[8];
  float CC, R;
  init_state(cost, base, c, U, CC, R);

  const int Ts = *Tsample;                 // uniform
  const int P = (Ts > 2) ? (Ts - 2) : 0;   // P+1 <= Ts <= T

  for (int i = 0; i < P; ++i) fast_iter(U, c, CC, R);

  int ib = MAXIT;
  for (int i = P + 1; i <= MAXIT; ++i) {
    float ds = chk_iter(U, c, CC, R);
    if (__all(ds <= 0.04f)) { ib = i; break; }
  }
  // ib = max(P+1, wave-max Tr) <= T; the argmax wave reports exactly T.

  // fp16 checkpoint of z(ib) = 0.05*U - 0.05*CC  (z in [-1.5,1.5])
  const float CC05 = 0.05f * CC;
  uint32_t pk[8];
#pragma unroll
  for (int j = 0; j < 8; ++j) {
    float zx = __builtin_fmaf(0.05f, U[j].x, -CC05);
    float zy = __builtin_fmaf(0.05f, U[j].y, -CC05);
    h2v h = __builtin_amdgcn_cvt_pkrtz(zx, zy);
    pk[j] = *(uint32_t*)&h;
  }
  const int ub = base >> 1;                // 2 elems per uint
  *(uint4*)(zh + ub)     = make_uint4(pk[0], pk[1], pk[2], pk[3]);
  *(uint4*)(zh + ub + 4) = make_uint4(pk[4], pk[5], pk[6], pk[7]);
  if (lane == 0) {
    TrArr[gw] = ib;
    atomicMax(Tglob, ib);
  }
}

// --- pass2: resume ib -> T, +1 differentiable step, clamp, store -----------
__global__ __launch_bounds__(256, 4) void dys_pass2(
    const float* __restrict__ cost, const int* __restrict__ Tglob,
    const int* __restrict__ TrArr, const uint32_t* __restrict__ zh,
    float* __restrict__ out) {
  const int lane = threadIdx.x & 63;
  const int gw = blockIdx.x * 4 + (threadIdx.x >> 6);
  const int base = (gw * RPW + (lane >> 2)) * 64 + (lane & 3) * 16;

  v2f c[8], U[8];
  load_c(cost, base, c);
  const int ub = base >> 1;
  const uint4 pa = *(const uint4*)(zh + ub);
  const uint4 pb = *(const uint4*)(zh + ub + 4);
  uint32_t pk[8] = {pa.x, pa.y, pa.z, pa.w, pb.x, pb.y, pb.z, pb.w};
  float r = 0.0f;
#pragma unroll
  for (int j = 0; j < 8; ++j) {
    h2v h = *(h2v*)&pk[j];
    float zx = (float)h.x, zy = (float)h.y;
    U[j].x = 20.0f * zx;
    U[j].y = 20.0f * zy;
    r += (zx + zy);
    r = __builtin_fmaf(0.05f, c[j].x + c[j].y, r);
  }
  float CC = 0.0f;
  float R = reduce4(r);                    // R = Sz + a*Sc (invariant)

  const int T = *Tglob;
  const int ib = TrArr[gw];                // wave-uniform

  // (T - ib) lockstep iters to z(T), +1 differentiable step
  for (int i = ib; i <= T; ++i) fast_iter(U, c, CC, R);

  const float CC05 = 0.05f * CC;
#pragma unroll
  for (int k = 0; k < 2; ++k) {
    float4 o;
    o.x = __builtin_amdgcn_fmed3f(
        __builtin_fmaf(0.05f, U[4 * k + 0].x, -CC05), 0.0f, 1.0f);
    o.y = __builtin_amdgcn_fmed3f(
        __builtin_fmaf(0.05f, U[4 * k + 0].y, -CC05), 0.0f, 1.0f);
    o.z = __builtin_amdgcn_fmed3f(
        __builtin_fmaf(0.05f, U[4 * k + 1].x, -CC05), 0.0f, 1.0f);
    o.w = __builtin_amdgcn_fmed3f(
        __builtin_fmaf(0.05f, U[4 * k + 1].y, -CC05), 0.0f, 1.0f);
    *(float4*)(out + base + 8 * k) = o;
    float4 p;
    p.x = __builtin_amdgcn_fmed3f(
        __builtin_fmaf(0.05f, U[4 * k + 2].x, -CC05), 0.0f, 1.0f);
    p.y = __builtin_amdgcn_fmed3f(
        __builtin_fmaf(0.05f, U[4 * k + 2].y, -CC05), 0.0f, 1.0f);
    p.z = __builtin_amdgcn_fmed3f(
        __builtin_fmaf(0.05f, U[4 * k + 3].x, -CC05), 0.0f, 1.0f);
    p.w = __builtin_amdgcn_fmed3f(
        __builtin_fmaf(0.05f, U[4 * k + 3].y, -CC05), 0.0f, 1.0f);
    *(float4*)(out + base + 8 * k + 4) = p;
  }
}

extern "C" void kernel_launch(void* const* d_in, const int* in_sizes, int n_in,
                              void* d_out, int out_size, void* d_ws,
                              size_t ws_size, hipStream_t stream) {
  const float* cost = (const float*)d_in[0];
  float* out = (float*)d_out;

  // ws: [0..4) Tglob ; [4..8) Tsample ; [1024..) TrArr[16384] ; then fp16 ckpt
  int* Tglob   = (int*)d_ws;
  int* Tsample = (int*)d_ws + 1;
  const size_t TR_OFF = 1024;
  const size_t Z_OFF  = TR_OFF + (size_t)NWAVES * sizeof(int);  // 16B-aligned
  int*      TrArr = (int*)((char*)d_ws + TR_OFF);
  uint32_t* zh    = (uint32_t*)((char*)d_ws + Z_OFF);           // 32 MB

  (void)Tglob;
  (void)hipMemsetAsync(d_ws, 0, 8, stream);   // Tglob = Tsample = 0

  dim3 block(256);
  dys_probe<<<dim3(PROBE_WAVES / 4), block, 0, stream>>>(cost, Tsample);
  dys_pass1<<<dim3(NWAVES / 4), block, 0, stream>>>(cost, Tsample, Tglob,
                                                    TrArr, zh);
  dys_pass2<<<dim3(NWAVES / 4), block, 0, stream>>>(cost, Tglob, TrArr, zh,
                                                    out);
}

// Round 13
// 414.054 us; speedup vs baseline: 1.3131x; 1.3131x over previous
//
#include <hip/hip_runtime.h>
#include <cstdint>

// ---------------------------------------------------------------------------
// dysOpt: Davis-Yin splitting, 262144 rows x 64 vars, dynamic T.
//
// u-space iteration (u = z + C): m = med3(u, C, C+1) = clamp(z,0,1) + C;
// u+ = K1*m - ac  (ac = 0.05*c; update independent of the reduction).
//
// ROUND-13 NILPOTENT COLLAPSE of the (C,R) scalar chain: with
//   C+ = (K1-K2)C - R/64 + (K2/64)Sm - 0.5 ,  R+ = 64C + R - Sm + 32
// and K1-K2 = -1 exactly, the system matrix M = [[-1,-1/64],[64,1]] has
// tr=0, det=0 => M^2 = 0 and M*const = 0. State memory depth 2:
//   C_{t+1} = (K2/64)*Sm_t - (K1/64)*Sm_{t-1} - 0.5      (exact in R)
// seeded by virtual Sm_{-1} = R0/K1. Replaces the 22-cyc scalar chain with
// 2 fma + 1 add (~10 cyc) and breaks the serial C<-R dependency.
// Rounding: C recomputed fresh each iter (no accumulation); ~ulp/iter,
// damped by the K1=0.9975 contraction (absmax at bf16 floor for 8 rounds).
//
// Cost model (fits r2..r12 within ~10%): 3-src VALU (fma/med3) ~4 cyc/wave64,
// VOP2 ~2 cyc; VOP3P pk >= scalar pair (r12 regression); shfl = LDS pipe,
// free when VALU-bound & sparse (r6), deadly when dense (r8).
// r6 core = 198 cyc/wave-iter (best); this removes ~12 -> ~186.
//
// Structure: probe (8192 rows, 512 waves = 1 occupancy round, checked every
// iter) -> Ts = max Tr <= T; pass1: P = Ts-2 fast iters, then checked to
// wave all-pass = ib (monotone residual => argmax wave reports exactly T);
// fp16 checkpoint z(ib) (cvt_pkrtz, z in [-1.5,1.5], err<=1e-3 -- proven
// r12), atomicMax T. pass2: resume ib -> T, +1 differentiable step, clamp,
// store. Check: ||dz||^2 = q2 - 2*dC*q1 + 64*dC^2 <= TOL^2 = 1e-4.
// ---------------------------------------------------------------------------

#ifndef JAX_PARTITIONABLE
#define JAX_PARTITIONABLE 1
#endif

#define BATCHN 262144
#define MAXIT  200
#define RPW    16                         // rows per wave (4 lanes/row)
#define NWAVES (BATCHN / RPW)             // 16384
#define PROBE_ROWS 8192
#define PROBE_WAVES (PROBE_ROWS / RPW)    // 512

#define K1f 0.9975f
// compile-time doubles -> correctly rounded floats
#define KAf ((float)((1.0 + (double)K1f) / 64.0))   // K2/64
#define KBf ((float)(((double)K1f) / 64.0))         // K1/64
#define RINVf ((float)(1.0 / (double)K1f))          // for virtual Sm_{-1}

typedef __fp16 h2v __attribute__((ext_vector_type(2)));

__device__ __forceinline__ void tf2x32(uint32_t x0, uint32_t x1,
                                       uint32_t& o0, uint32_t& o1) {
  const uint32_t k0 = 0u, k1 = 1u;                 // jax.random.key(1) -> [0,1]
  const uint32_t k2 = 0x1BD11BDAu ^ k0 ^ k1;
  x0 += k0; x1 += k1;
#define TFR(r) { x0 += x1; x1 = (x1 << (r)) | (x1 >> (32 - (r))); x1 ^= x0; }
  TFR(13) TFR(15) TFR(26) TFR(6)   x0 += k1; x1 += k2 + 1u;
  TFR(17) TFR(29) TFR(16) TFR(24)  x0 += k2; x1 += k0 + 2u;
  TFR(13) TFR(15) TFR(26) TFR(6)   x0 += k0; x1 += k1 + 3u;
  TFR(17) TFR(29) TFR(16) TFR(24)  x0 += k1; x1 += k2 + 4u;
  TFR(13) TFR(15) TFR(26) TFR(6)   x0 += k2; x1 += k0 + 5u;
#undef TFR
  o0 = x0; o1 = x1;
}

__device__ __forceinline__ float z0_at(uint32_t f) {
  uint32_t b;
#if JAX_PARTITIONABLE
  uint32_t o0, o1;
  tf2x32(0u, f, o0, o1);
  b = o0 ^ o1;
#else
  const uint32_t H = 8388608u;
  uint32_t lo = (f < H) ? f : (f - H);
  uint32_t o0, o1;
  tf2x32(lo, lo + H, o0, o1);
  b = (f < H) ? o0 : o1;
#endif
  return __uint_as_float((b >> 9) | 0x3f800000u) - 1.0f;
}

// 4-lane row reduction (lanes xor 1,2 hold one row) -- LDS pipe, sparse use
__device__ __forceinline__ float reduce4(float v) {
  v += __shfl_xor(v, 1);
  v += __shfl_xor(v, 2);
  return v;
}

__device__ __forceinline__ float tsum16(const float* a) {
  float b0 = a[0] + a[1],  b1 = a[2] + a[3],  b2 = a[4] + a[5],
        b3 = a[6] + a[7],  b4 = a[8] + a[9],  b5 = a[10] + a[11],
        b6 = a[12] + a[13], b7 = a[14] + a[15];
  float c0 = b0 + b1, c1 = b2 + b3, c2 = b4 + b5, c3 = b6 + b7;
  return (c0 + c1) + (c2 + c3);
}

// ---- fast iteration: no convergence check ---------------------------------
__device__ __forceinline__ void fast_iter(float u[16], const float ac[16],
                                          float& C, float& Chi, float& Smp) {
  float m[16];
#pragma unroll
  for (int j = 0; j < 16; ++j) m[j] = __builtin_amdgcn_fmed3f(u[j], C, Chi);
  float s = tsum16(m);
#pragma unroll
  for (int j = 0; j < 16; ++j) u[j] = __builtin_fmaf(K1f, m[j], -ac[j]);
  s = reduce4(s);                                   // Sm over the row
  float Cn = __builtin_fmaf(KAf, s, __builtin_fmaf(-KBf, Smp, -0.5f));
  Smp = s;
  C = Cn;
  Chi = Cn + 1.0f;
}

// ---- checked iteration: returns ||dz_row||^2 (replicated in the row) ------
__device__ __forceinline__ float chk_iter(float u[16], const float ac[16],
                                          float& C, float& Chi, float& Smp) {
  float m[16];
#pragma unroll
  for (int j = 0; j < 16; ++j) m[j] = __builtin_amdgcn_fmed3f(u[j], C, Chi);
  float s = tsum16(m);
  float q1 = 0.0f, q2 = 0.0f;
#pragma unroll
  for (int j = 0; j < 16; ++j) {
    float un = __builtin_fmaf(K1f, m[j], -ac[j]);
    float d = un - u[j];
    q1 += d;
    q2 = __builtin_fmaf(d, d, q2);
    u[j] = un;
  }
  s = reduce4(s);
  float Cn = __builtin_fmaf(KAf, s, __builtin_fmaf(-KBf, Smp, -0.5f));
  float dC = Cn - C;
  Smp = s;
  C = Cn;
  Chi = Cn + 1.0f;
  q1 = reduce4(q1);
  q2 = reduce4(q2);
  // ||dz||^2 = q2 - 2*dC*q1 + 64*dC^2
  float a = __builtin_fmaf(64.0f, dC, -2.0f * q1);
  return __builtin_fmaf(dC, a, q2);
}

__device__ __forceinline__ void load_ac(const float* __restrict__ cost,
                                        int base, float ac[16]) {
#pragma unroll
  for (int k = 0; k < 4; ++k) {
    const float4 cq = *(const float4*)(cost + base + 4 * k);
    ac[4 * k + 0] = 0.05f * cq.x; ac[4 * k + 1] = 0.05f * cq.y;
    ac[4 * k + 2] = 0.05f * cq.z; ac[4 * k + 3] = 0.05f * cq.w;
  }
}

__device__ __forceinline__ void init_state(const float* __restrict__ cost,
                                           int base, float ac[16], float u[16],
                                           float& C, float& Chi, float& Smp) {
  load_ac(cost, base, ac);
  float r = 0.0f;
#pragma unroll
  for (int j = 0; j < 16; ++j) {
    u[j] = z0_at((uint32_t)(base + j));   // u = z0, C = 0
    r += u[j] + ac[j];
  }
  float R = reduce4(r);                   // R0 = Sz + a*Sc
  C = 0.0f; Chi = 1.0f;
  Smp = R * RINVf;                        // virtual Sm_{-1} = R0/K1
}

// --- probe: rows [0, PROBE_ROWS), checked every iter, atomicMax Ts ---------
__global__ __launch_bounds__(256) void dys_probe(
    const float* __restrict__ cost, int* __restrict__ Tsample) {
  const int lane = threadIdx.x & 63;
  const int gw = blockIdx.x * 4 + (threadIdx.x >> 6);
  const int base = (gw * RPW + (lane >> 2)) * 64 + (lane & 3) * 16;

  float ac[16], u[16], C, Chi, Smp;
  init_state(cost, base, ac, u, C, Chi, Smp);

  int ib = MAXIT;
  for (int i = 1; i <= MAXIT; ++i) {
    float ds = chk_iter(u, ac, C, Chi, Smp);
    if (__all(ds <= 1.0e-4f)) { ib = i; break; }   // wave-max Tr
  }
  if (lane == 0) atomicMax(Tsample, ib);
}

// --- pass1: P fast iters, checked to wave all-pass; fp16 checkpoint --------
__global__ __launch_bounds__(256) void dys_pass1(
    const float* __restrict__ cost, const int* __restrict__ Tsample,
    int* __restrict__ Tglob, int* __restrict__ TrArr,
    uint32_t* __restrict__ zh) {
  const int lane = threadIdx.x & 63;
  const int gw = blockIdx.x * 4 + (threadIdx.x >> 6);
  const int base = (gw * RPW + (lane >> 2)) * 64 + (lane & 3) * 16;

  float ac[16], u[16], C, Chi, Smp;
  init_state(cost, base, ac, u, C, Chi, Smp);

  const int Ts = *Tsample;                 // uniform
  const int P = (Ts > 2) ? (Ts - 2) : 0;   // P+1 <= Ts <= T

  for (int i = 0; i < P; ++i) fast_iter(u, ac, C, Chi, Smp);

  int ib = MAXIT;
  for (int i = P + 1; i <= MAXIT; ++i) {
    float ds = chk_iter(u, ac, C, Chi, Smp);
    if (__all(ds <= 1.0e-4f)) { ib = i; break; }
  }
  // ib = max(P+1, wave-max Tr) <= T; the argmax wave reports exactly T.

  // fp16 checkpoint of z(ib) = u - C   (z in [-1.5,1.5])
  uint32_t pk[8];
#pragma unroll
  for (int j = 0; j < 8; ++j) {
    float zx = u[2 * j] - C;
    float zy = u[2 * j + 1] - C;
    h2v h = __builtin_amdgcn_cvt_pkrtz(zx, zy);
    pk[j] = *(uint32_t*)&h;
  }
  const int ub = base >> 1;                // 2 elems per uint
  *(uint4*)(zh + ub)     = make_uint4(pk[0], pk[1], pk[2], pk[3]);
  *(uint4*)(zh + ub + 4) = make_uint4(pk[4], pk[5], pk[6], pk[7]);
  if (lane == 0) {
    TrArr[gw] = ib;
    atomicMax(Tglob, ib);
  }
}

// --- pass2: resume ib -> T, +1 differentiable step, clamp, store -----------
__global__ __launch_bounds__(256) void dys_pass2(
    const float* __restrict__ cost, const int* __restrict__ Tglob,
    const int* __restrict__ TrArr, const uint32_t* __restrict__ zh,
    float* __restrict__ out) {
  const int lane = threadIdx.x & 63;
  const int gw = blockIdx.x * 4 + (threadIdx.x >> 6);
  const int base = (gw * RPW + (lane >> 2)) * 64 + (lane & 3) * 16;

  float ac[16], u[16];
  load_ac(cost, base, ac);
  const int ub = base >> 1;
  const uint4 pa = *(const uint4*)(zh + ub);
  const uint4 pb = *(const uint4*)(zh + ub + 4);
  uint32_t pk[8] = {pa.x, pa.y, pa.z, pa.w, pb.x, pb.y, pb.z, pb.w};
  float r = 0.0f;
#pragma unroll
  for (int j = 0; j < 8; ++j) {
    h2v h = *(h2v*)&pk[j];
    u[2 * j]     = (float)h.x;
    u[2 * j + 1] = (float)h.y;
    r += ((float)h.x + ac[2 * j]) + ((float)h.y + ac[2 * j + 1]);
  }
  float R = reduce4(r);                    // R0 at resume
  float C = 0.0f, Chi = 1.0f;
  float Smp = R * RINVf;                   // virtual Sm_{-1}

  const int T = *Tglob;
  const int ib = TrArr[gw];                // wave-uniform

  // (T - ib) lockstep iters to z(T), +1 differentiable step
  for (int i = ib; i <= T; ++i) fast_iter(u, ac, C, Chi, Smp);

#pragma unroll
  for (int k = 0; k < 4; ++k) {
    float4 o;
    o.x = __builtin_amdgcn_fmed3f(u[4 * k + 0] - C, 0.0f, 1.0f);
    o.y = __builtin_amdgcn_fmed3f(u[4 * k + 1] - C, 0.0f, 1.0f);
    o.z = __builtin_amdgcn_fmed3f(u[4 * k + 2] - C, 0.0f, 1.0f);
    o.w = __builtin_amdgcn_fmed3f(u[4 * k + 3] - C, 0.0f, 1.0f);
    *(float4*)(out + base + 4 * k) = o;
  }
}

extern "C" void kernel_launch(void* const* d_in, const int* in_sizes, int n_in,
                              void* d_out, int out_size, void* d_ws,
                              size_t ws_size, hipStream_t stream) {
  const float* cost = (const float*)d_in[0];
  float* out = (float*)d_out;

  // ws: [0..4) Tglob ; [4..8) Tsample ; [1024..) TrArr[16384] ; then fp16 ckpt
  int* Tglob   = (int*)d_ws;
  int* Tsample = (int*)d_ws + 1;
  const size_t TR_OFF = 1024;
  const size_t Z_OFF  = TR_OFF + (size_t)NWAVES * sizeof(int);  // 16B-aligned
  int*      TrArr = (int*)((char*)d_ws + TR_OFF);
  uint32_t* zh    = (uint32_t*)((char*)d_ws + Z_OFF);           // 32 MB

  (void)hipMemsetAsync(d_ws, 0, 8, stream);   // Tglob = Tsample = 0

  dim3 block(256);
  dys_probe<<<dim3(PROBE_WAVES / 4), block, 0, stream>>>(cost, Tsample);
  dys_pass1<<<dim3(NWAVES / 4), block, 0, stream>>>(cost, Tsample, Tglob,
                                                    TrArr, zh);
  dys_pass2<<<dim3(NWAVES / 4), block, 0, stream>>>(cost, Tglob, TrArr, zh,
                                                    out);
}